// Round 1
// baseline (121.251 us; speedup 1.0000x reference)
//
#include <hip/hip_runtime.h>
#include <cfloat>

#define BLOCK 256
#define TS 1024      // cloud-B points staged in LDS per tile (12 KB)
#define KSPLIT 16    // split of the M dimension for grid parallelism

__global__ void init_min_kernel(unsigned int* buf, int n) {
    int i = blockIdx.x * blockDim.x + threadIdx.x;
    if (i < n) buf[i] = 0x7F800000u;  // +inf
}

// For each point in A, min squared distance to points in B[slice], atomicMin into minbuf.
__global__ __launch_bounds__(BLOCK) void chamfer_min_kernel(
    const float* __restrict__ A, int N,
    const float* __restrict__ B, int M,
    unsigned int* __restrict__ minbuf)
{
    __shared__ float tile[TS * 3];
    const int tid = threadIdx.x;
    const int a_idx = blockIdx.x * BLOCK + tid;

    const int mlen = (M + KSPLIT - 1) / KSPLIT;
    const int m0 = blockIdx.y * mlen;
    const int m1 = min(m0 + mlen, M);

    float ax = 0.f, ay = 0.f, az = 0.f;
    if (a_idx < N) {
        ax = A[a_idx * 3 + 0];
        ay = A[a_idx * 3 + 1];
        az = A[a_idx * 3 + 2];
    }
    float m = FLT_MAX;

    for (int t0 = m0; t0 < m1; t0 += TS) {
        const int tcount = min(TS, m1 - t0);
        const int nflt = tcount * 3;
        const int nv4 = nflt >> 2;
        // slice starts are 16B-aligned when mlen*3*4 and TS*3*4 are multiples of 16 (true here)
        const float4* __restrict__ src4 = (const float4*)(B + (size_t)t0 * 3);
        float4* dst4 = (float4*)tile;
        for (int v = tid; v < nv4; v += BLOCK) dst4[v] = src4[v];
        for (int v = (nv4 << 2) + tid; v < nflt; v += BLOCK) tile[v] = B[(size_t)t0 * 3 + v];
        __syncthreads();

        int j = 0;
        for (; j + 4 <= tcount; j += 4) {
            const float4* p = (const float4*)(tile + j * 3);  // j%4==0 -> 48B steps, 16B aligned
            float4 q0 = p[0], q1 = p[1], q2 = p[2];
            float dx, dy, dz, d;
            dx = ax - q0.x; dy = ay - q0.y; dz = az - q0.z;
            d = fmaf(dx, dx, fmaf(dy, dy, dz * dz)); m = fminf(m, d);
            dx = ax - q0.w; dy = ay - q1.x; dz = az - q1.y;
            d = fmaf(dx, dx, fmaf(dy, dy, dz * dz)); m = fminf(m, d);
            dx = ax - q1.z; dy = ay - q1.w; dz = az - q2.x;
            d = fmaf(dx, dx, fmaf(dy, dy, dz * dz)); m = fminf(m, d);
            dx = ax - q2.y; dy = ay - q2.z; dz = az - q2.w;
            d = fmaf(dx, dx, fmaf(dy, dy, dz * dz)); m = fminf(m, d);
        }
        for (; j < tcount; ++j) {
            float dx = ax - tile[j * 3 + 0];
            float dy = ay - tile[j * 3 + 1];
            float dz = az - tile[j * 3 + 2];
            float d = fmaf(dx, dx, fmaf(dy, dy, dz * dz));
            m = fminf(m, d);
        }
        __syncthreads();
    }

    if (a_idx < N) atomicMin(&minbuf[a_idx], __float_as_uint(m));
}

__global__ __launch_bounds__(BLOCK) void chamfer_reduce_kernel(
    const unsigned int* __restrict__ min1, int N,
    const unsigned int* __restrict__ min2, int M,
    float* __restrict__ out)
{
    __shared__ double sdata[BLOCK];
    const int tid = threadIdx.x;
    double s1 = 0.0, s2 = 0.0;
    for (int i = tid; i < N; i += BLOCK) s1 += (double)__uint_as_float(min1[i]);
    for (int i = tid; i < M; i += BLOCK) s2 += (double)__uint_as_float(min2[i]);
    double s = s1 / (double)N + s2 / (double)M;
    sdata[tid] = s;
    __syncthreads();
    for (int st = BLOCK / 2; st > 0; st >>= 1) {
        if (tid < st) sdata[tid] += sdata[tid + st];
        __syncthreads();
    }
    if (tid == 0) out[0] = (float)sdata[0];
}

extern "C" void kernel_launch(void* const* d_in, const int* in_sizes, int n_in,
                              void* d_out, int out_size, void* d_ws, size_t ws_size,
                              hipStream_t stream) {
    const float* pc1 = (const float*)d_in[0];
    const float* pc2 = (const float*)d_in[1];
    const int N = in_sizes[0] / 3;
    const int M = in_sizes[1] / 3;

    unsigned int* min1 = (unsigned int*)d_ws;
    unsigned int* min2 = min1 + N;
    float* out = (float*)d_out;

    const int tot = N + M;
    init_min_kernel<<<(tot + BLOCK - 1) / BLOCK, BLOCK, 0, stream>>>(min1, tot);

    dim3 grid1((N + BLOCK - 1) / BLOCK, KSPLIT);
    chamfer_min_kernel<<<grid1, BLOCK, 0, stream>>>(pc1, N, pc2, M, min1);

    dim3 grid2((M + BLOCK - 1) / BLOCK, KSPLIT);
    chamfer_min_kernel<<<grid2, BLOCK, 0, stream>>>(pc2, M, pc1, N, min2);

    chamfer_reduce_kernel<<<1, BLOCK, 0, stream>>>(min1, N, min2, M, out);
}

// Round 2
// 80.249 us; speedup vs baseline: 1.5109x; 1.5109x over previous
//
#include <hip/hip_runtime.h>
#include <cfloat>

#define BLOCK 256
#define TS 1024      // cloud-B points staged in LDS per tile (16 KB as float4)
#define KSPLIT 16    // split of the M dimension for grid parallelism
#define RBLOCK 1024

__global__ void init_min_kernel(unsigned int* buf, int n) {
    int i = blockIdx.x * blockDim.x + threadIdx.x;
    if (i < n) buf[i] = 0x7F800000u;  // +inf
}

// For each point a in A, minimize f(b) = 0.5|b|^2 - a.b over B[slice];
// d_min = 2*f_min + |a|^2. Inner loop: 3 fma + 1 min per pair.
__global__ __launch_bounds__(BLOCK) void chamfer_min_kernel(
    const float* __restrict__ A, int N,
    const float* __restrict__ B, int M,
    unsigned int* __restrict__ minbuf)
{
    __shared__ float4 tile[TS];  // (bx, by, bz, 0.5*|b|^2)
    const int tid = threadIdx.x;
    const int a_idx = blockIdx.x * BLOCK + tid;

    const int mlen = (M + KSPLIT - 1) / KSPLIT;
    const int m0 = blockIdx.y * mlen;
    const int m1 = min(m0 + mlen, M);

    float ax = 0.f, ay = 0.f, az = 0.f;
    if (a_idx < N) {
        ax = A[a_idx * 3 + 0];
        ay = A[a_idx * 3 + 1];
        az = A[a_idx * 3 + 2];
    }
    const float nax = -ax, nay = -ay, naz = -az;
    const float a2 = fmaf(ax, ax, fmaf(ay, ay, az * az));

    float mm0 = FLT_MAX, mm1 = FLT_MAX, mm2 = FLT_MAX, mm3 = FLT_MAX;

    for (int t0 = m0; t0 < m1; t0 += TS) {
        const int tcount = min(TS, m1 - t0);

        // ---- stage B[t0 .. t0+tcount) into LDS as (x,y,z,h) ----
        {
            const int full4 = tcount >> 2;  // groups of 4 points (48B = 3 float4)
            const float4* __restrict__ src4 = (const float4*)(B + (size_t)t0 * 3);
            for (int g = tid; g < full4; g += BLOCK) {
                float4 qa = src4[3 * g + 0];
                float4 qb = src4[3 * g + 1];
                float4 qc = src4[3 * g + 2];
                float4 p;
                p.x = qa.x; p.y = qa.y; p.z = qa.z;
                p.w = 0.5f * fmaf(p.x, p.x, fmaf(p.y, p.y, p.z * p.z));
                tile[4 * g + 0] = p;
                p.x = qa.w; p.y = qb.x; p.z = qb.y;
                p.w = 0.5f * fmaf(p.x, p.x, fmaf(p.y, p.y, p.z * p.z));
                tile[4 * g + 1] = p;
                p.x = qb.z; p.y = qb.w; p.z = qc.x;
                p.w = 0.5f * fmaf(p.x, p.x, fmaf(p.y, p.y, p.z * p.z));
                tile[4 * g + 2] = p;
                p.x = qc.y; p.y = qc.z; p.z = qc.w;
                p.w = 0.5f * fmaf(p.x, p.x, fmaf(p.y, p.y, p.z * p.z));
                tile[4 * g + 3] = p;
            }
            for (int j = (full4 << 2) + tid; j < tcount; j += BLOCK) {
                float bx = B[(size_t)(t0 + j) * 3 + 0];
                float by = B[(size_t)(t0 + j) * 3 + 1];
                float bz = B[(size_t)(t0 + j) * 3 + 2];
                float4 p;
                p.x = bx; p.y = by; p.z = bz;
                p.w = 0.5f * fmaf(bx, bx, fmaf(by, by, bz * bz));
                tile[j] = p;
            }
        }
        __syncthreads();

        int j = 0;
        for (; j + 8 <= tcount; j += 8) {
            float4 q0 = tile[j + 0];
            float4 q1 = tile[j + 1];
            float4 q2 = tile[j + 2];
            float4 q3 = tile[j + 3];
            float t0v, t1v, t2v, t3v;
            t0v = fmaf(nax, q0.x, q0.w); t0v = fmaf(nay, q0.y, t0v); t0v = fmaf(naz, q0.z, t0v);
            t1v = fmaf(nax, q1.x, q1.w); t1v = fmaf(nay, q1.y, t1v); t1v = fmaf(naz, q1.z, t1v);
            t2v = fmaf(nax, q2.x, q2.w); t2v = fmaf(nay, q2.y, t2v); t2v = fmaf(naz, q2.z, t2v);
            t3v = fmaf(nax, q3.x, q3.w); t3v = fmaf(nay, q3.y, t3v); t3v = fmaf(naz, q3.z, t3v);
            mm0 = fminf(mm0, t0v); mm1 = fminf(mm1, t1v);
            mm2 = fminf(mm2, t2v); mm3 = fminf(mm3, t3v);
            float4 q4 = tile[j + 4];
            float4 q5 = tile[j + 5];
            float4 q6 = tile[j + 6];
            float4 q7 = tile[j + 7];
            t0v = fmaf(nax, q4.x, q4.w); t0v = fmaf(nay, q4.y, t0v); t0v = fmaf(naz, q4.z, t0v);
            t1v = fmaf(nax, q5.x, q5.w); t1v = fmaf(nay, q5.y, t1v); t1v = fmaf(naz, q5.z, t1v);
            t2v = fmaf(nax, q6.x, q6.w); t2v = fmaf(nay, q6.y, t2v); t2v = fmaf(naz, q6.z, t2v);
            t3v = fmaf(nax, q7.x, q7.w); t3v = fmaf(nay, q7.y, t3v); t3v = fmaf(naz, q7.z, t3v);
            mm0 = fminf(mm0, t0v); mm1 = fminf(mm1, t1v);
            mm2 = fminf(mm2, t2v); mm3 = fminf(mm3, t3v);
        }
        for (; j < tcount; ++j) {
            float4 q = tile[j];
            float t = fmaf(nax, q.x, q.w);
            t = fmaf(nay, q.y, t);
            t = fmaf(naz, q.z, t);
            mm0 = fminf(mm0, t);
        }
        __syncthreads();
    }

    if (a_idx < N) {
        float m = fminf(fminf(mm0, mm1), fminf(mm2, mm3));
        float d = fmaf(2.0f, m, a2);   // |a-b|^2 = 2*(0.5|b|^2 - a.b) + |a|^2
        d = fmaxf(d, 0.0f);            // protect uint-ordered atomicMin from tiny negatives
        atomicMin(&minbuf[a_idx], __float_as_uint(d));
    }
}

__global__ __launch_bounds__(RBLOCK) void chamfer_reduce_kernel(
    const unsigned int* __restrict__ min1, int N,
    const unsigned int* __restrict__ min2, int M,
    float* __restrict__ out)
{
    __shared__ double warp_sums[RBLOCK / 64];
    const int tid = threadIdx.x;
    double s = 0.0;

    const double invN = 1.0 / (double)N;
    const uint4* p1 = (const uint4*)min1;
    for (int i = tid; i < (N >> 2); i += RBLOCK) {
        uint4 v = p1[i];
        s += ((double)__uint_as_float(v.x) + (double)__uint_as_float(v.y) +
              (double)__uint_as_float(v.z) + (double)__uint_as_float(v.w)) * invN;
    }
    for (int i = ((N >> 2) << 2) + tid; i < N; i += RBLOCK)
        s += (double)__uint_as_float(min1[i]) * invN;

    const double invM = 1.0 / (double)M;
    const uint4* p2 = (const uint4*)min2;
    for (int i = tid; i < (M >> 2); i += RBLOCK) {
        uint4 v = p2[i];
        s += ((double)__uint_as_float(v.x) + (double)__uint_as_float(v.y) +
              (double)__uint_as_float(v.z) + (double)__uint_as_float(v.w)) * invM;
    }
    for (int i = ((M >> 2) << 2) + tid; i < M; i += RBLOCK)
        s += (double)__uint_as_float(min2[i]) * invM;

    // wave-level reduce (64 lanes)
    for (int off = 32; off > 0; off >>= 1)
        s += __shfl_down(s, off, 64);
    const int wave = tid >> 6;
    if ((tid & 63) == 0) warp_sums[wave] = s;
    __syncthreads();
    if (tid == 0) {
        double tot = 0.0;
        for (int w = 0; w < RBLOCK / 64; ++w) tot += warp_sums[w];
        out[0] = (float)tot;
    }
}

extern "C" void kernel_launch(void* const* d_in, const int* in_sizes, int n_in,
                              void* d_out, int out_size, void* d_ws, size_t ws_size,
                              hipStream_t stream) {
    const float* pc1 = (const float*)d_in[0];
    const float* pc2 = (const float*)d_in[1];
    const int N = in_sizes[0] / 3;
    const int M = in_sizes[1] / 3;

    unsigned int* min1 = (unsigned int*)d_ws;
    unsigned int* min2 = min1 + N;
    float* out = (float*)d_out;

    const int tot = N + M;
    init_min_kernel<<<(tot + BLOCK - 1) / BLOCK, BLOCK, 0, stream>>>(min1, tot);

    dim3 grid1((N + BLOCK - 1) / BLOCK, KSPLIT);
    chamfer_min_kernel<<<grid1, BLOCK, 0, stream>>>(pc1, N, pc2, M, min1);

    dim3 grid2((M + BLOCK - 1) / BLOCK, KSPLIT);
    chamfer_min_kernel<<<grid2, BLOCK, 0, stream>>>(pc2, M, pc1, N, min2);

    chamfer_reduce_kernel<<<1, RBLOCK, 0, stream>>>(min1, N, min2, M, out);
}

// Round 3
// 65.519 us; speedup vs baseline: 1.8506x; 1.2248x over previous
//
#include <hip/hip_runtime.h>
#include <cfloat>

#define BLOCK 256
#define AU 4         // cloud-A points per thread (registers)
#define TS 512       // cloud-B points staged per LDS tile (8 KB as float4)
#define KSPLIT 32    // split of the M dimension for grid parallelism
#define RBLOCK 1024

__global__ void init_min_kernel(unsigned int* buf, int n) {
    int i = blockIdx.x * blockDim.x + threadIdx.x;
    if (i < n) buf[i] = 0x7F800000u;  // +inf
}

// For each point a in A, minimize f(b) = 0.5|b|^2 - a.b over B[slice];
// d_min = 2*f_min + |a|^2. Inner loop per (a,b): 3 fma + 1 min.
// Each thread owns AU a-points so one LDS broadcast read feeds AU pairs.
__global__ __launch_bounds__(BLOCK) void chamfer_min_kernel(
    const float* __restrict__ A, int N,
    const float* __restrict__ B, int M,
    unsigned int* __restrict__ minbuf)
{
    __shared__ float4 tile[TS];  // (bx, by, bz, 0.5*|b|^2)
    const int tid = threadIdx.x;
    const int abase = blockIdx.x * (BLOCK * AU) + tid;

    const int mlen = (M + KSPLIT - 1) / KSPLIT;
    const int m0 = blockIdx.y * mlen;
    const int m1 = min(m0 + mlen, M);

    float nax[AU], nay[AU], naz[AU];
    #pragma unroll
    for (int u = 0; u < AU; ++u) {
        const int ai = abase + u * BLOCK;
        float x = 0.f, y = 0.f, z = 0.f;
        if (ai < N) {
            x = A[(size_t)ai * 3 + 0];
            y = A[(size_t)ai * 3 + 1];
            z = A[(size_t)ai * 3 + 2];
        }
        nax[u] = -x; nay[u] = -y; naz[u] = -z;
    }

    float mm[AU][2];
    #pragma unroll
    for (int u = 0; u < AU; ++u) { mm[u][0] = FLT_MAX; mm[u][1] = FLT_MAX; }

    for (int t0 = m0; t0 < m1; t0 += TS) {
        const int tcount = min(TS, m1 - t0);

        // lane-contiguous staging: thread j writes tile[j] (conflict-free)
        for (int j = tid; j < tcount; j += BLOCK) {
            const size_t s = (size_t)(t0 + j) * 3;
            float bx = B[s + 0], by = B[s + 1], bz = B[s + 2];
            float4 p;
            p.x = bx; p.y = by; p.z = bz;
            p.w = 0.5f * fmaf(bx, bx, fmaf(by, by, bz * bz));
            tile[j] = p;
        }
        __syncthreads();

        int j = 0;
        for (; j + 4 <= tcount; j += 4) {
            float4 q0 = tile[j + 0];
            float4 q1 = tile[j + 1];
            float4 q2 = tile[j + 2];
            float4 q3 = tile[j + 3];
            #pragma unroll
            for (int u = 0; u < AU; ++u) {
                float t0v = fmaf(nax[u], q0.x, q0.w);
                t0v = fmaf(nay[u], q0.y, t0v);
                t0v = fmaf(naz[u], q0.z, t0v);
                float t1v = fmaf(nax[u], q1.x, q1.w);
                t1v = fmaf(nay[u], q1.y, t1v);
                t1v = fmaf(naz[u], q1.z, t1v);
                float t2v = fmaf(nax[u], q2.x, q2.w);
                t2v = fmaf(nay[u], q2.y, t2v);
                t2v = fmaf(naz[u], q2.z, t2v);
                float t3v = fmaf(nax[u], q3.x, q3.w);
                t3v = fmaf(nay[u], q3.y, t3v);
                t3v = fmaf(naz[u], q3.z, t3v);
                mm[u][0] = fminf(mm[u][0], fminf(t0v, t2v));
                mm[u][1] = fminf(mm[u][1], fminf(t1v, t3v));
            }
        }
        for (; j < tcount; ++j) {
            float4 q = tile[j];
            #pragma unroll
            for (int u = 0; u < AU; ++u) {
                float t = fmaf(nax[u], q.x, q.w);
                t = fmaf(nay[u], q.y, t);
                t = fmaf(naz[u], q.z, t);
                mm[u][0] = fminf(mm[u][0], t);
            }
        }
        __syncthreads();
    }

    #pragma unroll
    for (int u = 0; u < AU; ++u) {
        const int ai = abase + u * BLOCK;
        if (ai < N) {
            const float a2 = fmaf(nax[u], nax[u], fmaf(nay[u], nay[u], naz[u] * naz[u]));
            float m = fminf(mm[u][0], mm[u][1]);
            float d = fmaf(2.0f, m, a2);   // |a-b|^2 = 2*(0.5|b|^2 - a.b) + |a|^2
            d = fmaxf(d, 0.0f);            // keep uint-ordered atomicMin valid
            atomicMin(&minbuf[ai], __float_as_uint(d));
        }
    }
}

__global__ __launch_bounds__(RBLOCK) void chamfer_reduce_kernel(
    const unsigned int* __restrict__ min1, int N,
    const unsigned int* __restrict__ min2, int M,
    float* __restrict__ out)
{
    __shared__ double warp_sums[RBLOCK / 64];
    const int tid = threadIdx.x;
    double s = 0.0;

    const double invN = 1.0 / (double)N;
    const uint4* p1 = (const uint4*)min1;
    for (int i = tid; i < (N >> 2); i += RBLOCK) {
        uint4 v = p1[i];
        s += ((double)__uint_as_float(v.x) + (double)__uint_as_float(v.y) +
              (double)__uint_as_float(v.z) + (double)__uint_as_float(v.w)) * invN;
    }
    for (int i = ((N >> 2) << 2) + tid; i < N; i += RBLOCK)
        s += (double)__uint_as_float(min1[i]) * invN;

    const double invM = 1.0 / (double)M;
    const uint4* p2 = (const uint4*)min2;
    for (int i = tid; i < (M >> 2); i += RBLOCK) {
        uint4 v = p2[i];
        s += ((double)__uint_as_float(v.x) + (double)__uint_as_float(v.y) +
              (double)__uint_as_float(v.z) + (double)__uint_as_float(v.w)) * invM;
    }
    for (int i = ((M >> 2) << 2) + tid; i < M; i += RBLOCK)
        s += (double)__uint_as_float(min2[i]) * invM;

    for (int off = 32; off > 0; off >>= 1)
        s += __shfl_down(s, off, 64);
    const int wave = tid >> 6;
    if ((tid & 63) == 0) warp_sums[wave] = s;
    __syncthreads();
    if (tid == 0) {
        double tot = 0.0;
        for (int w = 0; w < RBLOCK / 64; ++w) tot += warp_sums[w];
        out[0] = (float)tot;
    }
}

extern "C" void kernel_launch(void* const* d_in, const int* in_sizes, int n_in,
                              void* d_out, int out_size, void* d_ws, size_t ws_size,
                              hipStream_t stream) {
    const float* pc1 = (const float*)d_in[0];
    const float* pc2 = (const float*)d_in[1];
    const int N = in_sizes[0] / 3;
    const int M = in_sizes[1] / 3;

    unsigned int* min1 = (unsigned int*)d_ws;
    unsigned int* min2 = min1 + N;
    float* out = (float*)d_out;

    const int tot = N + M;
    init_min_kernel<<<(tot + BLOCK - 1) / BLOCK, BLOCK, 0, stream>>>(min1, tot);

    dim3 grid1((N + BLOCK * AU - 1) / (BLOCK * AU), KSPLIT);
    chamfer_min_kernel<<<grid1, BLOCK, 0, stream>>>(pc1, N, pc2, M, min1);

    dim3 grid2((M + BLOCK * AU - 1) / (BLOCK * AU), KSPLIT);
    chamfer_min_kernel<<<grid2, BLOCK, 0, stream>>>(pc2, M, pc1, N, min2);

    chamfer_reduce_kernel<<<1, RBLOCK, 0, stream>>>(min1, N, min2, M, out);
}

// Round 4
// 55.598 us; speedup vs baseline: 2.1809x; 1.1785x over previous
//
#include <hip/hip_runtime.h>
#include <cfloat>

#define BLOCK 256
#define AU 4         // cloud-A points per thread (registers)
#define TS 256       // cloud-B points staged per LDS tile (4 KB as float4)
#define KSPLIT 64    // split of the B dimension for grid parallelism
#define RBLOCK 256

// Both directions in one launch (blockIdx.z selects). For each point a in A,
// minimize f(b) = 0.5|b|^2 - a.b over B[slice]; d = 2*f_min + |a|^2.
// Inner loop per (a,b): 3 fma + 0.5 min3. Partial mins written per slice
// (no atomics, no init, deterministic).
__global__ __launch_bounds__(BLOCK, 4) void chamfer_min_kernel(
    const float* __restrict__ pc1, int N,
    const float* __restrict__ pc2, int M,
    float* __restrict__ P1, float* __restrict__ P2)
{
    __shared__ float4 tile[TS];  // (bx, by, bz, 0.5*|b|^2)
    const int tid = threadIdx.x;

    const float* A; const float* B; float* P; int An, Bn;
    if (blockIdx.z == 0) { A = pc1; An = N; B = pc2; Bn = M; P = P1; }
    else                 { A = pc2; An = M; B = pc1; Bn = N; P = P2; }

    const int abase = blockIdx.x * (BLOCK * AU) + tid;
    const int mlen = (Bn + KSPLIT - 1) / KSPLIT;
    const int m0 = blockIdx.y * mlen;
    const int m1 = min(m0 + mlen, Bn);

    float nax[AU], nay[AU], naz[AU];
    #pragma unroll
    for (int u = 0; u < AU; ++u) {
        const int ai = abase + u * BLOCK;
        float x = 0.f, y = 0.f, z = 0.f;
        if (ai < An) {
            x = A[(size_t)ai * 3 + 0];
            y = A[(size_t)ai * 3 + 1];
            z = A[(size_t)ai * 3 + 2];
        }
        nax[u] = -x; nay[u] = -y; naz[u] = -z;
    }

    float mm0[AU], mm1[AU];
    #pragma unroll
    for (int u = 0; u < AU; ++u) { mm0[u] = FLT_MAX; mm1[u] = FLT_MAX; }

    for (int t0 = m0; t0 < m1; t0 += TS) {
        const int tcount = min(TS, m1 - t0);

        // lane-contiguous staging: thread j writes tile[j] (conflict-free)
        for (int j = tid; j < tcount; j += BLOCK) {
            const size_t s = (size_t)(t0 + j) * 3;
            float bx = B[s + 0], by = B[s + 1], bz = B[s + 2];
            float4 p;
            p.x = bx; p.y = by; p.z = bz;
            p.w = 0.5f * fmaf(bx, bx, fmaf(by, by, bz * bz));
            tile[j] = p;
        }
        __syncthreads();

#define GROUP4(J) { \
        float4 q0 = tile[(J) + 0]; \
        float4 q1 = tile[(J) + 1]; \
        float4 q2 = tile[(J) + 2]; \
        float4 q3 = tile[(J) + 3]; \
        _Pragma("unroll") \
        for (int u = 0; u < AU; ++u) { \
            float t0v = fmaf(nax[u], q0.x, q0.w); t0v = fmaf(nay[u], q0.y, t0v); t0v = fmaf(naz[u], q0.z, t0v); \
            float t1v = fmaf(nax[u], q1.x, q1.w); t1v = fmaf(nay[u], q1.y, t1v); t1v = fmaf(naz[u], q1.z, t1v); \
            float t2v = fmaf(nax[u], q2.x, q2.w); t2v = fmaf(nay[u], q2.y, t2v); t2v = fmaf(naz[u], q2.z, t2v); \
            float t3v = fmaf(nax[u], q3.x, q3.w); t3v = fmaf(nay[u], q3.y, t3v); t3v = fmaf(naz[u], q3.z, t3v); \
            mm0[u] = fminf(mm0[u], fminf(t0v, t2v)); \
            mm1[u] = fminf(mm1[u], fminf(t1v, t3v)); \
        } }

        if (tcount == TS) {
            #pragma unroll 2
            for (int j = 0; j < TS; j += 4) GROUP4(j)
        } else {
            int j = 0;
            for (; j + 4 <= tcount; j += 4) GROUP4(j)
            for (; j < tcount; ++j) {
                float4 q = tile[j];
                #pragma unroll
                for (int u = 0; u < AU; ++u) {
                    float t = fmaf(nax[u], q.x, q.w);
                    t = fmaf(nay[u], q.y, t);
                    t = fmaf(naz[u], q.z, t);
                    mm0[u] = fminf(mm0[u], t);
                }
            }
        }
#undef GROUP4
        __syncthreads();
    }

    #pragma unroll
    for (int u = 0; u < AU; ++u) {
        const int ai = abase + u * BLOCK;
        if (ai < An) {
            const float a2 = fmaf(nax[u], nax[u], fmaf(nay[u], nay[u], naz[u] * naz[u]));
            float d = fmaf(2.0f, fminf(mm0[u], mm1[u]), a2);
            P[(size_t)blockIdx.y * An + ai] = fmaxf(d, 0.0f);
        }
    }
}

// Stage 1: one thread per point; min across KSPLIT partials, scaled partial mean.
__global__ __launch_bounds__(RBLOCK) void chamfer_reduce1_kernel(
    const float* __restrict__ P1, int N,
    const float* __restrict__ P2, int M,
    double* __restrict__ bsum)
{
    const int tid = threadIdx.x;
    const int g = blockIdx.x * RBLOCK + tid;
    double s = 0.0;
    const int T = N + M;
    if (g < T) {
        const float* base; int stride, i; double scale;
        if (g < N) { base = P1; stride = N; i = g;     scale = 1.0 / (double)N; }
        else       { base = P2; stride = M; i = g - N; scale = 1.0 / (double)M; }
        float v = FLT_MAX;
        #pragma unroll 16
        for (int k = 0; k < KSPLIT; ++k)
            v = fminf(v, base[(size_t)k * stride + i]);
        s = (double)v * scale;
    }
    // wave reduce (64 lanes) then block reduce
    for (int off = 32; off > 0; off >>= 1)
        s += __shfl_down(s, off, 64);
    __shared__ double wsum[RBLOCK / 64];
    if ((tid & 63) == 0) wsum[tid >> 6] = s;
    __syncthreads();
    if (tid == 0) {
        double tot = 0.0;
        #pragma unroll
        for (int w = 0; w < RBLOCK / 64; ++w) tot += wsum[w];
        bsum[blockIdx.x] = tot;
    }
}

// Stage 2: single block sums the per-block doubles.
__global__ __launch_bounds__(RBLOCK) void chamfer_reduce2_kernel(
    const double* __restrict__ bsum, int nb, float* __restrict__ out)
{
    const int tid = threadIdx.x;
    double s = 0.0;
    for (int i = tid; i < nb; i += RBLOCK) s += bsum[i];
    for (int off = 32; off > 0; off >>= 1)
        s += __shfl_down(s, off, 64);
    __shared__ double wsum[RBLOCK / 64];
    if ((tid & 63) == 0) wsum[tid >> 6] = s;
    __syncthreads();
    if (tid == 0) {
        double tot = 0.0;
        #pragma unroll
        for (int w = 0; w < RBLOCK / 64; ++w) tot += wsum[w];
        out[0] = (float)tot;
    }
}

extern "C" void kernel_launch(void* const* d_in, const int* in_sizes, int n_in,
                              void* d_out, int out_size, void* d_ws, size_t ws_size,
                              hipStream_t stream) {
    const float* pc1 = (const float*)d_in[0];
    const float* pc2 = (const float*)d_in[1];
    const int N = in_sizes[0] / 3;
    const int M = in_sizes[1] / 3;

    float* P1 = (float*)d_ws;                       // [KSPLIT][N]
    float* P2 = P1 + (size_t)KSPLIT * N;            // [KSPLIT][M]
    double* bsum = (double*)(P2 + (size_t)KSPLIT * M);
    float* out = (float*)d_out;

    const int maxNM = (N > M) ? N : M;
    const int gx = (maxNM + BLOCK * AU - 1) / (BLOCK * AU);
    dim3 grid(gx, KSPLIT, 2);
    chamfer_min_kernel<<<grid, BLOCK, 0, stream>>>(pc1, N, pc2, M, P1, P2);

    const int gr = (N + M + RBLOCK - 1) / RBLOCK;
    chamfer_reduce1_kernel<<<gr, RBLOCK, 0, stream>>>(P1, N, P2, M, bsum);
    chamfer_reduce2_kernel<<<1, RBLOCK, 0, stream>>>(bsum, gr, out);
}

// Round 5
// 53.981 us; speedup vs baseline: 2.2462x; 1.0299x over previous
//
#include <hip/hip_runtime.h>
#include <cfloat>

#define BLOCK 256
#define AU 8         // cloud-A points per thread (registers)
#define TS 256       // cloud-B points staged per LDS tile (4 KB as float4)
#define KSPLIT 64    // split of the B dimension for grid parallelism
#define RBLOCK 256

// Both directions in one launch (blockIdx.z selects). For each point a in A,
// minimize f(b) = 0.5|b|^2 - a.b over B[slice]; d = 2*f_min + |a|^2.
// One broadcast ds_read_b128 per B-point feeds AU=8 pairs -> LDS pipe no
// longer the limiter; inner loop is 3 fma + 0.5 min3 per pair.
__global__ __launch_bounds__(BLOCK, 4) void chamfer_min_kernel(
    const float* __restrict__ pc1, int N,
    const float* __restrict__ pc2, int M,
    float* __restrict__ P1, float* __restrict__ P2)
{
    __shared__ float4 tile[TS];  // (bx, by, bz, 0.5*|b|^2)
    const int tid = threadIdx.x;

    const float* A; const float* B; float* P; int An, Bn;
    if (blockIdx.z == 0) { A = pc1; An = N; B = pc2; Bn = M; P = P1; }
    else                 { A = pc2; An = M; B = pc1; Bn = N; P = P2; }

    const int abase = blockIdx.x * (BLOCK * AU) + tid;
    const int mlen = (Bn + KSPLIT - 1) / KSPLIT;
    const int m0 = blockIdx.y * mlen;
    const int m1 = min(m0 + mlen, Bn);

    float nax[AU], nay[AU], naz[AU];
    #pragma unroll
    for (int u = 0; u < AU; ++u) {
        const int ai = abase + u * BLOCK;
        float x = 0.f, y = 0.f, z = 0.f;
        if (ai < An) {
            x = A[(size_t)ai * 3 + 0];
            y = A[(size_t)ai * 3 + 1];
            z = A[(size_t)ai * 3 + 2];
        }
        nax[u] = -x; nay[u] = -y; naz[u] = -z;
    }

    float mm0[AU], mm1[AU];
    #pragma unroll
    for (int u = 0; u < AU; ++u) { mm0[u] = FLT_MAX; mm1[u] = FLT_MAX; }

    for (int t0 = m0; t0 < m1; t0 += TS) {
        const int tcount = min(TS, m1 - t0);

        // lane-contiguous staging: thread j writes tile[j] (conflict-free)
        for (int j = tid; j < tcount; j += BLOCK) {
            const size_t s = (size_t)(t0 + j) * 3;
            float bx = B[s + 0], by = B[s + 1], bz = B[s + 2];
            float4 p;
            p.x = bx; p.y = by; p.z = bz;
            p.w = 0.5f * fmaf(bx, bx, fmaf(by, by, bz * bz));
            tile[j] = p;
        }
        __syncthreads();

#define GROUP4(J) { \
        float4 q0 = tile[(J) + 0]; \
        float4 q1 = tile[(J) + 1]; \
        float4 q2 = tile[(J) + 2]; \
        float4 q3 = tile[(J) + 3]; \
        _Pragma("unroll") \
        for (int u = 0; u < AU; ++u) { \
            float t0v = fmaf(nax[u], q0.x, q0.w); t0v = fmaf(nay[u], q0.y, t0v); t0v = fmaf(naz[u], q0.z, t0v); \
            float t1v = fmaf(nax[u], q1.x, q1.w); t1v = fmaf(nay[u], q1.y, t1v); t1v = fmaf(naz[u], q1.z, t1v); \
            float t2v = fmaf(nax[u], q2.x, q2.w); t2v = fmaf(nay[u], q2.y, t2v); t2v = fmaf(naz[u], q2.z, t2v); \
            float t3v = fmaf(nax[u], q3.x, q3.w); t3v = fmaf(nay[u], q3.y, t3v); t3v = fmaf(naz[u], q3.z, t3v); \
            mm0[u] = fminf(fminf(mm0[u], t0v), t2v); /* v_min3 */ \
            mm1[u] = fminf(fminf(mm1[u], t1v), t3v); /* v_min3 */ \
        } }

        if (tcount == TS) {
            #pragma unroll 2
            for (int j = 0; j < TS; j += 4) GROUP4(j)
        } else {
            int j = 0;
            for (; j + 4 <= tcount; j += 4) GROUP4(j)
            for (; j < tcount; ++j) {
                float4 q = tile[j];
                #pragma unroll
                for (int u = 0; u < AU; ++u) {
                    float t = fmaf(nax[u], q.x, q.w);
                    t = fmaf(nay[u], q.y, t);
                    t = fmaf(naz[u], q.z, t);
                    mm0[u] = fminf(mm0[u], t);
                }
            }
        }
#undef GROUP4
        __syncthreads();
    }

    #pragma unroll
    for (int u = 0; u < AU; ++u) {
        const int ai = abase + u * BLOCK;
        if (ai < An) {
            const float a2 = fmaf(nax[u], nax[u], fmaf(nay[u], nay[u], naz[u] * naz[u]));
            float d = fmaf(2.0f, fminf(mm0[u], mm1[u]), a2);
            P[(size_t)blockIdx.y * An + ai] = fmaxf(d, 0.0f);
        }
    }
}

// Stage 1: one thread per point; min across KSPLIT partials, scaled partial mean.
__global__ __launch_bounds__(RBLOCK) void chamfer_reduce1_kernel(
    const float* __restrict__ P1, int N,
    const float* __restrict__ P2, int M,
    double* __restrict__ bsum)
{
    const int tid = threadIdx.x;
    const int g = blockIdx.x * RBLOCK + tid;
    double s = 0.0;
    const int T = N + M;
    if (g < T) {
        const float* base; int stride, i; double scale;
        if (g < N) { base = P1; stride = N; i = g;     scale = 1.0 / (double)N; }
        else       { base = P2; stride = M; i = g - N; scale = 1.0 / (double)M; }
        float v = FLT_MAX;
        #pragma unroll 16
        for (int k = 0; k < KSPLIT; ++k)
            v = fminf(v, base[(size_t)k * stride + i]);
        s = (double)v * scale;
    }
    for (int off = 32; off > 0; off >>= 1)
        s += __shfl_down(s, off, 64);
    __shared__ double wsum[RBLOCK / 64];
    if ((tid & 63) == 0) wsum[tid >> 6] = s;
    __syncthreads();
    if (tid == 0) {
        double tot = 0.0;
        #pragma unroll
        for (int w = 0; w < RBLOCK / 64; ++w) tot += wsum[w];
        bsum[blockIdx.x] = tot;
    }
}

// Stage 2: single block sums the per-block doubles.
__global__ __launch_bounds__(RBLOCK) void chamfer_reduce2_kernel(
    const double* __restrict__ bsum, int nb, float* __restrict__ out)
{
    const int tid = threadIdx.x;
    double s = 0.0;
    for (int i = tid; i < nb; i += RBLOCK) s += bsum[i];
    for (int off = 32; off > 0; off >>= 1)
        s += __shfl_down(s, off, 64);
    __shared__ double wsum[RBLOCK / 64];
    if ((tid & 63) == 0) wsum[tid >> 6] = s;
    __syncthreads();
    if (tid == 0) {
        double tot = 0.0;
        #pragma unroll
        for (int w = 0; w < RBLOCK / 64; ++w) tot += wsum[w];
        out[0] = (float)tot;
    }
}

extern "C" void kernel_launch(void* const* d_in, const int* in_sizes, int n_in,
                              void* d_out, int out_size, void* d_ws, size_t ws_size,
                              hipStream_t stream) {
    const float* pc1 = (const float*)d_in[0];
    const float* pc2 = (const float*)d_in[1];
    const int N = in_sizes[0] / 3;
    const int M = in_sizes[1] / 3;

    float* P1 = (float*)d_ws;                       // [KSPLIT][N]
    float* P2 = P1 + (size_t)KSPLIT * N;            // [KSPLIT][M]
    double* bsum = (double*)(P2 + (size_t)KSPLIT * M);
    float* out = (float*)d_out;

    const int maxNM = (N > M) ? N : M;
    const int gx = (maxNM + BLOCK * AU - 1) / (BLOCK * AU);
    dim3 grid(gx, KSPLIT, 2);
    chamfer_min_kernel<<<grid, BLOCK, 0, stream>>>(pc1, N, pc2, M, P1, P2);

    const int gr = (N + M + RBLOCK - 1) / RBLOCK;
    chamfer_reduce1_kernel<<<gr, RBLOCK, 0, stream>>>(P1, N, P2, M, bsum);
    chamfer_reduce2_kernel<<<1, RBLOCK, 0, stream>>>(bsum, gr, out);
}